// Round 1
// baseline (198.979 us; speedup 1.0000x reference)
//
#include <hip/hip_runtime.h>
#include <math.h>

#define IN_DIM 1024
#define OUT_DIM 1024
#define NROWS 8192
#define KDIM 4096   // 4 knots * IN_DIM

typedef __attribute__((ext_vector_type(8))) short bf16x8;
typedef __attribute__((ext_vector_type(4))) float f32x4;

static __device__ __forceinline__ unsigned short f2bf(float f) {
  union { float f; unsigned u; } v; v.f = f;
  unsigned u = v.u;
  return (unsigned short)((u + 0x7fffu + ((u >> 16) & 1u)) >> 16);  // RTNE
}

// ---- prep A: coef[b][k] and A4[b][k*IN_DIM+i] = bf16(coef[b][k] * x[b][i])
__global__ __launch_bounds__(256) void prep_a_kernel(
    const float* __restrict__ x, unsigned short* __restrict__ A4,
    float* __restrict__ coef)
{
  const int b = blockIdx.x;
  const float* xr = x + (size_t)b * (IN_DIM + 1);
  const float phase = xr[IN_DIM];
  const float ps = 4.0f * phase;
  const int ip = (int)ps;            // truncation, matches astype(int32)
  const int i1 = ip & 3;
  const float mu = ps - (float)ip;   // == mod(ps, 1.0)
  const float mu2 = mu * mu, mu3 = mu2 * mu;
  const float c0 = -0.5f * mu3 +        mu2 - 0.5f * mu;
  const float c1 =  1.5f * mu3 - 2.5f * mu2 + 1.0f;
  const float c2 = -1.5f * mu3 + 2.0f * mu2 + 0.5f * mu;
  const float c3 =  0.5f * mu3 - 0.5f * mu2;
  float w[4];
  w[(i1 + 3) & 3] = c0;   // idx[0] = (i1-1) mod 4
  w[i1]           = c1;   // idx[1] = i1
  w[(i1 + 1) & 3] = c2;   // idx[2]
  w[(i1 + 2) & 3] = c3;   // idx[3]
  if (threadIdx.x < 4) coef[b * 4 + threadIdx.x] = w[threadIdx.x];

  const int i = threadIdx.x * 4;     // 256 threads * 4 = 1024 elems
  const float f0 = xr[i], f1 = xr[i + 1], f2 = xr[i + 2], f3 = xr[i + 3];
  unsigned short* arow = A4 + (size_t)b * KDIM;
  #pragma unroll
  for (int k = 0; k < 4; k++) {
    ushort4 vv;
    vv.x = f2bf(w[k] * f0);
    vv.y = f2bf(w[k] * f1);
    vv.z = f2bf(w[k] * f2);
    vv.w = f2bf(w[k] * f3);
    *reinterpret_cast<ushort4*>(arow + k * IN_DIM + i) = vv;
  }
}

// ---- prep W: Wb[o][k*IN_DIM+i] = bf16(W[k][o][i])  (N-major, K contiguous)
__global__ __launch_bounds__(256) void prep_w_kernel(
    const float* __restrict__ W, unsigned short* __restrict__ Wb)
{
  const int t = blockIdx.x * 256 + threadIdx.x;   // 0 .. 1048575
  const int flat = t * 4;                         // element index into W
  const int k = flat >> 20;
  const int o = (flat >> 10) & 1023;
  const int i = flat & 1023;
  const float4 f = *reinterpret_cast<const float4*>(W + flat);
  ushort4 vv;
  vv.x = f2bf(f.x); vv.y = f2bf(f.y); vv.z = f2bf(f.z); vv.w = f2bf(f.w);
  *reinterpret_cast<ushort4*>(Wb + (size_t)o * KDIM + k * IN_DIM + i) = vv;
}

// ---- GEMM: C(8192x1024) = A4(8192x4096) . Wb^T, bias+elu epilogue
#define BM 128
#define BN 128
#define BK 64

__global__ __launch_bounds__(256, 2) void gemm_kernel(
    const unsigned short* __restrict__ A4,
    const unsigned short* __restrict__ Wb,
    const float* __restrict__ coef,
    const float* __restrict__ bias,
    float* __restrict__ out)
{
  __shared__ unsigned short As[BM * BK];   // 16 KB, rows of 64 bf16 (128 B)
  __shared__ unsigned short Bs[BN * BK];   // 16 KB

  const int tid  = threadIdx.x;
  const int wave = tid >> 6;
  const int lane = tid & 63;
  const int row0 = blockIdx.y * BM;
  const int col0 = blockIdx.x * BN;

  // staging: thread t -> LDS byte offset t*16 (wave-uniform base + lane*16)
  const int srow = tid >> 3;           // 0..31 (per issue of 32 rows)
  const int scol = (tid & 7) * 8;      // element col, 8-elem (16 B) chunks

  const int wr  = (wave >> 1) * 64;    // wave sub-tile origin
  const int wc  = (wave & 1) * 64;
  const int fm  = lane & 15;           // fragment m/n index
  const int fko = (lane >> 4) * 8;     // k-octet start

  f32x4 acc[4][4];
  const f32x4 zero = {0.f, 0.f, 0.f, 0.f};
  #pragma unroll
  for (int a = 0; a < 4; a++)
    #pragma unroll
    for (int b = 0; b < 4; b++)
      acc[a][b] = zero;

  const unsigned short* Abase = A4 + (size_t)row0 * KDIM;
  const unsigned short* Bbase = Wb + (size_t)col0 * KDIM;

  for (int kb = 0; kb < KDIM; kb += BK) {
    #pragma unroll
    for (int it = 0; it < 4; it++) {
      const int r = srow + it * 32;
      __builtin_amdgcn_global_load_lds(
          (const __attribute__((address_space(1))) void*)(Abase + (size_t)r * KDIM + kb + scol),
          (__attribute__((address_space(3))) void*)(As + r * BK + scol), 16, 0, 0);
      __builtin_amdgcn_global_load_lds(
          (const __attribute__((address_space(1))) void*)(Bbase + (size_t)r * KDIM + kb + scol),
          (__attribute__((address_space(3))) void*)(Bs + r * BK + scol), 16, 0, 0);
    }
    __syncthreads();   // compiler emits vmcnt(0) drain before s_barrier

    #pragma unroll
    for (int kk = 0; kk < BK; kk += 32) {
      bf16x8 af[4], bfr[4];
      #pragma unroll
      for (int mi = 0; mi < 4; mi++)
        af[mi] = *reinterpret_cast<const bf16x8*>(As + (wr + mi * 16 + fm) * BK + kk + fko);
      #pragma unroll
      for (int ni = 0; ni < 4; ni++)
        bfr[ni] = *reinterpret_cast<const bf16x8*>(Bs + (wc + ni * 16 + fm) * BK + kk + fko);
      #pragma unroll
      for (int mi = 0; mi < 4; mi++)
        #pragma unroll
        for (int ni = 0; ni < 4; ni++)
          acc[mi][ni] = __builtin_amdgcn_mfma_f32_16x16x32_bf16(
              af[mi], bfr[ni], acc[mi][ni], 0, 0, 0);
    }
    __syncthreads();
  }

  // epilogue: + sum_k coef[row][k]*bias[k][col], elu, fp32 store
  #pragma unroll
  for (int mi = 0; mi < 4; mi++) {
    const int rbase = row0 + wr + mi * 16 + ((lane >> 4) << 2);  // row = quad*4 + r
    const float4 cf0 = *reinterpret_cast<const float4*>(coef + (size_t)(rbase + 0) * 4);
    const float4 cf1 = *reinterpret_cast<const float4*>(coef + (size_t)(rbase + 1) * 4);
    const float4 cf2 = *reinterpret_cast<const float4*>(coef + (size_t)(rbase + 2) * 4);
    const float4 cf3 = *reinterpret_cast<const float4*>(coef + (size_t)(rbase + 3) * 4);
    const float4 cfs[4] = {cf0, cf1, cf2, cf3};
    #pragma unroll
    for (int ni = 0; ni < 4; ni++) {
      const int col = col0 + wc + ni * 16 + fm;                  // col = lane&15
      const float b0 = bias[col];
      const float b1 = bias[OUT_DIM + col];
      const float b2 = bias[2 * OUT_DIM + col];
      const float b3 = bias[3 * OUT_DIM + col];
      #pragma unroll
      for (int r = 0; r < 4; r++) {
        float v = acc[mi][ni][r]
                + cfs[r].x * b0 + cfs[r].y * b1 + cfs[r].z * b2 + cfs[r].w * b3;
        v = (v > 0.0f) ? v : expm1f(v);   // elu, alpha=1
        out[(size_t)(rbase + r) * OUT_DIM + col] = v;
      }
    }
  }
}

extern "C" void kernel_launch(void* const* d_in, const int* in_sizes, int n_in,
                              void* d_out, int out_size, void* d_ws, size_t ws_size,
                              hipStream_t stream) {
  const float* x  = (const float*)d_in[0];   // (8192, 1025)
  const float* wk = (const float*)d_in[1];   // (4, 1024, 1024)
  const float* bk = (const float*)d_in[2];   // (4, 1024)
  float* out = (float*)d_out;                // (8192, 1024) fp32

  char* ws = (char*)d_ws;
  float* coef          = (float*)ws;                                  // 128 KB
  unsigned short* Wb   = (unsigned short*)(ws + (128u << 10));        // 8 MB
  unsigned short* A4   = (unsigned short*)(ws + (128u << 10) + (8u << 20)); // 64 MB
  // total ws use: ~72.1 MB

  hipLaunchKernelGGL(prep_a_kernel, dim3(NROWS), dim3(256), 0, stream, x, A4, coef);
  hipLaunchKernelGGL(prep_w_kernel, dim3(4096), dim3(256), 0, stream, wk, Wb);
  hipLaunchKernelGGL(gemm_kernel, dim3(OUT_DIM / BN, NROWS / BM), dim3(256), 0, stream,
                     A4, Wb, coef, bk, out);
}

// Round 2
// 190.771 us; speedup vs baseline: 1.0430x; 1.0430x over previous
//
#include <hip/hip_runtime.h>
#include <math.h>

#define IN_DIM 1024
#define OUT_DIM 1024
#define NROWS 8192
#define KDIM 4096   // 4 knots * IN_DIM

typedef __attribute__((ext_vector_type(8))) short bf16x8;
typedef __attribute__((ext_vector_type(4))) float f32x4;

static __device__ __forceinline__ unsigned short f2bf(float f) {
  union { float f; unsigned u; } v; v.f = f;
  unsigned u = v.u;
  return (unsigned short)((u + 0x7fffu + ((u >> 16) & 1u)) >> 16);  // RTNE
}

// ---- prep A: coef[b][k] and A4[b][k*IN_DIM+i] = bf16(coef[b][k] * x[b][i])
// No arrays with runtime indices (scratch demotion!) — select chains only.
__global__ __launch_bounds__(256) void prep_a_kernel(
    const float* __restrict__ x, unsigned short* __restrict__ A4,
    float* __restrict__ coef)
{
  const int b = blockIdx.x;
  const float* xr = x + (size_t)b * (IN_DIM + 1);
  const float phase = xr[IN_DIM];
  const float ps = 4.0f * phase;
  const int ip = (int)ps;            // truncation, matches astype(int32), ps>=0
  const int i1 = ip & 3;
  const float mu = ps - (float)ip;   // == mod(ps, 1.0)
  const float mu2 = mu * mu, mu3 = mu2 * mu;
  const float c0 = -0.5f * mu3 +        mu2 - 0.5f * mu;
  const float c1 =  1.5f * mu3 - 2.5f * mu2 + 1.0f;
  const float c2 = -1.5f * mu3 + 2.0f * mu2 + 0.5f * mu;
  const float c3 =  0.5f * mu3 - 0.5f * mu2;
  // w_k = c_{(k - i1) mod 4 mapped: 0->c1,1->c2,2->c3,3->c0}
  const int d0 = (0 - i1) & 3, d1 = (1 - i1) & 3, d2 = (2 - i1) & 3, d3 = (3 - i1) & 3;
  const float w0 = d0 == 0 ? c1 : d0 == 1 ? c2 : d0 == 2 ? c3 : c0;
  const float w1 = d1 == 0 ? c1 : d1 == 1 ? c2 : d1 == 2 ? c3 : c0;
  const float w2 = d2 == 0 ? c1 : d2 == 1 ? c2 : d2 == 2 ? c3 : c0;
  const float w3 = d3 == 0 ? c1 : d3 == 1 ? c2 : d3 == 2 ? c3 : c0;
  if (threadIdx.x == 0) {
    float4 cv; cv.x = w0; cv.y = w1; cv.z = w2; cv.w = w3;
    *reinterpret_cast<float4*>(coef + (size_t)b * 4) = cv;
  }

  const int i = threadIdx.x * 4;     // 256 threads * 4 = 1024 elems
  const float f0 = xr[i], f1 = xr[i + 1], f2 = xr[i + 2], f3 = xr[i + 3];
  unsigned short* arow = A4 + (size_t)b * KDIM;
  ushort4 vv;
  vv.x = f2bf(w0 * f0); vv.y = f2bf(w0 * f1); vv.z = f2bf(w0 * f2); vv.w = f2bf(w0 * f3);
  *reinterpret_cast<ushort4*>(arow + 0 * IN_DIM + i) = vv;
  vv.x = f2bf(w1 * f0); vv.y = f2bf(w1 * f1); vv.z = f2bf(w1 * f2); vv.w = f2bf(w1 * f3);
  *reinterpret_cast<ushort4*>(arow + 1 * IN_DIM + i) = vv;
  vv.x = f2bf(w2 * f0); vv.y = f2bf(w2 * f1); vv.z = f2bf(w2 * f2); vv.w = f2bf(w2 * f3);
  *reinterpret_cast<ushort4*>(arow + 2 * IN_DIM + i) = vv;
  vv.x = f2bf(w3 * f0); vv.y = f2bf(w3 * f1); vv.z = f2bf(w3 * f2); vv.w = f2bf(w3 * f3);
  *reinterpret_cast<ushort4*>(arow + 3 * IN_DIM + i) = vv;
}

// ---- prep W: Wb[o][k*IN_DIM+i] = bf16(W[k][o][i])  (N-major, K contiguous)
__global__ __launch_bounds__(256) void prep_w_kernel(
    const float* __restrict__ W, unsigned short* __restrict__ Wb)
{
  const int t = blockIdx.x * 256 + threadIdx.x;   // 0 .. 1048575
  const int flat = t * 4;                         // element index into W
  const int k = flat >> 20;
  const int o = (flat >> 10) & 1023;
  const int i = flat & 1023;
  const float4 f = *reinterpret_cast<const float4*>(W + flat);
  ushort4 vv;
  vv.x = f2bf(f.x); vv.y = f2bf(f.y); vv.z = f2bf(f.z); vv.w = f2bf(f.w);
  *reinterpret_cast<ushort4*>(Wb + (size_t)o * KDIM + k * IN_DIM + i) = vv;
}

// ---- GEMM: C(8192x1024) = A4(8192x4096) . Wb^T, bias+elu epilogue
// LDS rows are 64 bf16 = 128 B = one full bank cycle -> naive chunk layout
// gives 16-way conflicts. XOR-swizzle: row r chunk c stored at slot c^(r&7).
// Swizzle applied on the GLOBAL source address so global_load_lds's
// lane-contiguous LDS dest (slot = tid*16B) is preserved.
#define BM 128
#define BN 128
#define BK 64

__global__ __launch_bounds__(256, 2) void gemm_kernel(
    const unsigned short* __restrict__ A4,
    const unsigned short* __restrict__ Wb,
    const float* __restrict__ coef,
    const float* __restrict__ bias,
    float* __restrict__ out)
{
  __shared__ unsigned short As[BM * BK];   // 16 KB
  __shared__ unsigned short Bs[BN * BK];   // 16 KB

  const int tid  = threadIdx.x;
  const int wave = tid >> 6;
  const int lane = tid & 63;
  const int row0 = blockIdx.y * BM;
  const int col0 = blockIdx.x * BN;

  // staging: thread t fills LDS slot t (byte offset t*16, lane-contiguous).
  // Slot (r, cc) must hold global chunk cc ^ (r&7).
  const int srow = tid >> 3;                          // 0..31 per issue
  const int scc  = tid & 7;                           // LDS chunk in row
  const int sgc  = (scc ^ (srow & 7)) * 8;            // global elem offset

  const int wr  = (wave >> 1) * 64;    // wave sub-tile origin
  const int wc  = (wave & 1) * 64;
  const int fm  = lane & 15;           // fragment m/n index
  const int fq  = lane >> 4;           // quad: k-octet index

  f32x4 acc[4][4];
  const f32x4 zero = {0.f, 0.f, 0.f, 0.f};
  #pragma unroll
  for (int a = 0; a < 4; a++)
    #pragma unroll
    for (int b = 0; b < 4; b++)
      acc[a][b] = zero;

  const unsigned short* Abase = A4 + (size_t)row0 * KDIM;
  const unsigned short* Bbase = Wb + (size_t)col0 * KDIM;

  for (int kb = 0; kb < KDIM; kb += BK) {
    #pragma unroll
    for (int it = 0; it < 4; it++) {
      const int r = srow + it * 32;    // (r&7)==(srow&7), swizzle unchanged
      __builtin_amdgcn_global_load_lds(
          (const __attribute__((address_space(1))) void*)(Abase + (size_t)r * KDIM + kb + sgc),
          (__attribute__((address_space(3))) void*)(As + r * BK + scc * 8), 16, 0, 0);
      __builtin_amdgcn_global_load_lds(
          (const __attribute__((address_space(1))) void*)(Bbase + (size_t)r * KDIM + kb + sgc),
          (__attribute__((address_space(3))) void*)(Bs + r * BK + scc * 8), 16, 0, 0);
    }
    __syncthreads();

    #pragma unroll
    for (int kk = 0; kk < BK; kk += 32) {
      bf16x8 af[4], bfr[4];
      #pragma unroll
      for (int mi = 0; mi < 4; mi++) {
        const int r = wr + mi * 16 + fm;
        const int lc = ((kk >> 3) + fq) ^ (fm & 7);   // swizzled chunk
        af[mi] = *reinterpret_cast<const bf16x8*>(As + r * BK + lc * 8);
      }
      #pragma unroll
      for (int ni = 0; ni < 4; ni++) {
        const int r = wc + ni * 16 + fm;
        const int lc = ((kk >> 3) + fq) ^ (fm & 7);
        bfr[ni] = *reinterpret_cast<const bf16x8*>(Bs + r * BK + lc * 8);
      }
      #pragma unroll
      for (int mi = 0; mi < 4; mi++)
        #pragma unroll
        for (int ni = 0; ni < 4; ni++)
          acc[mi][ni] = __builtin_amdgcn_mfma_f32_16x16x32_bf16(
              af[mi], bfr[ni], acc[mi][ni], 0, 0, 0);
    }
    __syncthreads();
  }

  // epilogue: + sum_k coef[row][k]*bias[k][col], elu, fp32 store
  #pragma unroll
  for (int mi = 0; mi < 4; mi++) {
    const int rbase = row0 + wr + mi * 16 + (fq << 2);   // row = quad*4 + r
    const float4 cf0 = *reinterpret_cast<const float4*>(coef + (size_t)(rbase + 0) * 4);
    const float4 cf1 = *reinterpret_cast<const float4*>(coef + (size_t)(rbase + 1) * 4);
    const float4 cf2 = *reinterpret_cast<const float4*>(coef + (size_t)(rbase + 2) * 4);
    const float4 cf3 = *reinterpret_cast<const float4*>(coef + (size_t)(rbase + 3) * 4);
    const float4 cfs[4] = {cf0, cf1, cf2, cf3};
    #pragma unroll
    for (int ni = 0; ni < 4; ni++) {
      const int col = col0 + wc + ni * 16 + fm;          // col = lane&15
      const float b0 = bias[col];
      const float b1 = bias[OUT_DIM + col];
      const float b2 = bias[2 * OUT_DIM + col];
      const float b3 = bias[3 * OUT_DIM + col];
      #pragma unroll
      for (int r = 0; r < 4; r++) {
        float v = acc[mi][ni][r]
                + cfs[r].x * b0 + cfs[r].y * b1 + cfs[r].z * b2 + cfs[r].w * b3;
        v = (v > 0.0f) ? v : expm1f(v);   // elu, alpha=1
        out[(size_t)(rbase + r) * OUT_DIM + col] = v;
      }
    }
  }
}

extern "C" void kernel_launch(void* const* d_in, const int* in_sizes, int n_in,
                              void* d_out, int out_size, void* d_ws, size_t ws_size,
                              hipStream_t stream) {
  const float* x  = (const float*)d_in[0];   // (8192, 1025)
  const float* wk = (const float*)d_in[1];   // (4, 1024, 1024)
  const float* bk = (const float*)d_in[2];   // (4, 1024)
  float* out = (float*)d_out;                // (8192, 1024) fp32

  char* ws = (char*)d_ws;
  float* coef          = (float*)ws;                                  // 128 KB
  unsigned short* Wb   = (unsigned short*)(ws + (128u << 10));        // 8 MB
  unsigned short* A4   = (unsigned short*)(ws + (128u << 10) + (8u << 20)); // 64 MB

  hipLaunchKernelGGL(prep_a_kernel, dim3(NROWS), dim3(256), 0, stream, x, A4, coef);
  hipLaunchKernelGGL(prep_w_kernel, dim3(4096), dim3(256), 0, stream, wk, Wb);
  hipLaunchKernelGGL(gemm_kernel, dim3(OUT_DIM / BN, NROWS / BM), dim3(256), 0, stream,
                     A4, Wb, coef, bk, out);
}

// Round 3
// 182.210 us; speedup vs baseline: 1.0920x; 1.0470x over previous
//
#include <hip/hip_runtime.h>
#include <math.h>

#define IN_DIM 1024
#define OUT_DIM 1024
#define NROWS 8192
#define XSTRIDE 1025   // x rows are 1024 feats + 1 phase

typedef __attribute__((ext_vector_type(8))) short bf16x8;
typedef __attribute__((ext_vector_type(4))) float f32x4;

static __device__ __forceinline__ unsigned short f2bf(float f) {
  union { float f; unsigned u; } v; v.f = f;
  unsigned u = v.u;
  return (unsigned short)((u + 0x7fffu + ((u >> 16) & 1u)) >> 16);  // RTNE
}

// ---- prep: blocks [0,4096) convert W -> Wb (bf16, [o][k*1024+i]);
//            blocks [4096,12288) convert feats -> F (bf16, [b][i], 2KB rows)
__global__ __launch_bounds__(256) void prep_kernel(
    const float* __restrict__ x, const float* __restrict__ W,
    unsigned short* __restrict__ Wb, unsigned short* __restrict__ F)
{
  const int blk = blockIdx.x;
  if (blk < 4096) {
    const int t = blk * 256 + threadIdx.x;    // 0 .. 1048575
    const int flat = t * 4;
    const int k = flat >> 20;
    const int o = (flat >> 10) & 1023;
    const int i = flat & 1023;
    const float4 f = *reinterpret_cast<const float4*>(W + flat);
    ushort4 vv;
    vv.x = f2bf(f.x); vv.y = f2bf(f.y); vv.z = f2bf(f.z); vv.w = f2bf(f.w);
    *reinterpret_cast<ushort4*>(Wb + (size_t)o * 4096 + k * 1024 + i) = vv;
  } else {
    const int b = blk - 4096;
    const float* xr = x + (size_t)b * XSTRIDE;
    const int i = threadIdx.x * 4;
    ushort4 vv;
    vv.x = f2bf(xr[i]); vv.y = f2bf(xr[i + 1]);
    vv.z = f2bf(xr[i + 2]); vv.w = f2bf(xr[i + 3]);
    *reinterpret_cast<ushort4*>(F + (size_t)b * 1024 + i) = vv;
  }
}

// ---- fused GEMM: out = elu( sum_k c_k(b) * (F . W_k^T + bias_k) )
// A-tile staged from bf16 F via registers with per-knot row scaling;
// B-tile via global_load_lds. XOR chunk swizzle keeps LDS reads conflict-free.
#define BM 128
#define BN 128
#define BK 64

__global__ __launch_bounds__(256, 2) void gemm_kernel(
    const unsigned short* __restrict__ F,    // 8192x1024 bf16
    const unsigned short* __restrict__ Wb,   // [o][k*1024+i] bf16
    const float* __restrict__ x,             // phase column source
    const float* __restrict__ bias,          // 4x1024 f32
    float* __restrict__ out)
{
  __shared__ unsigned short As[BM * BK];   // 16 KB
  __shared__ unsigned short Bs[BN * BK];   // 16 KB
  __shared__ float cfs[BM][4];             // 2 KB per-row knot coefs

  const int tid  = threadIdx.x;
  const int wave = tid >> 6;
  const int lane = tid & 63;
  const int row0 = blockIdx.y * BM;
  const int col0 = blockIdx.x * BN;

  // ---- prologue: per-row Catmull-Rom knot coefficients
  if (tid < BM) {
    const float phase = x[(size_t)(row0 + tid) * XSTRIDE + IN_DIM];
    const float ps = 4.0f * phase;
    const int ip = (int)ps;            // trunc, ps in [0,4)
    const int i1 = ip & 3;
    const float mu = ps - (float)ip;
    const float mu2 = mu * mu, mu3 = mu2 * mu;
    const float c0 = -0.5f * mu3 +        mu2 - 0.5f * mu;
    const float c1 =  1.5f * mu3 - 2.5f * mu2 + 1.0f;
    const float c2 = -1.5f * mu3 + 2.0f * mu2 + 0.5f * mu;
    const float c3 =  0.5f * mu3 - 0.5f * mu2;
    const int d0 = (0 - i1) & 3, d1 = (1 - i1) & 3, d2 = (2 - i1) & 3, d3 = (3 - i1) & 3;
    float4 cv;
    cv.x = d0 == 0 ? c1 : d0 == 1 ? c2 : d0 == 2 ? c3 : c0;
    cv.y = d1 == 0 ? c1 : d1 == 1 ? c2 : d1 == 2 ? c3 : c0;
    cv.z = d2 == 0 ? c1 : d2 == 1 ? c2 : d2 == 2 ? c3 : c0;
    cv.w = d3 == 0 ? c1 : d3 == 1 ? c2 : d3 == 2 ? c3 : c0;
    *reinterpret_cast<float4*>(cfs[tid]) = cv;
  }
  __syncthreads();

  // A staging geometry: thread -> row ar, 32-col half ac0 (one 16B uint4 = one 8-elem chunk)
  const int ar  = tid >> 1;
  const int ac0 = (tid & 1) * 32;
  const float4 cfr = *reinterpret_cast<const float4*>(cfs[ar]);

  // B staging geometry (global_load_lds, slot = tid*16B), XOR swizzle on source
  const int srow = tid >> 3;
  const int scc  = tid & 7;
  const int sgc  = (scc ^ (srow & 7)) * 8;

  const int wr = (wave >> 1) * 64;
  const int wc = (wave & 1) * 64;
  const int fm = lane & 15;
  const int fq = lane >> 4;

  f32x4 acc[4][4];
  const f32x4 zero = {0.f, 0.f, 0.f, 0.f};
  #pragma unroll
  for (int a = 0; a < 4; a++)
    #pragma unroll
    for (int b = 0; b < 4; b++)
      acc[a][b] = zero;

  const unsigned short* Arow  = F + (size_t)(row0 + ar) * 1024 + ac0;
  const unsigned short* Bbase = Wb + (size_t)col0 * 4096;

  for (int kb0 = 0; kb0 < 1024; kb0 += BK) {
    // load this thread's 32 bf16 A-elements once (reused for all 4 knots)
    uint4 araw[4];
    #pragma unroll
    for (int m = 0; m < 4; m++)
      araw[m] = *reinterpret_cast<const uint4*>(Arow + kb0 + m * 8);

    #pragma unroll
    for (int k = 0; k < 4; k++) {
      const float ck = (k == 0) ? cfr.x : (k == 1) ? cfr.y : (k == 2) ? cfr.z : cfr.w;
      // scale + round + pack each 16B chunk, ds_write to swizzled slot
      #pragma unroll
      for (int m = 0; m < 4; m++) {
        uint4 d = araw[m];
        uint4 r;
        #pragma unroll
        for (int j = 0; j < 4; j++) {
          const unsigned dj = (&d.x)[j];
          float lo = __uint_as_float(dj << 16);
          float hi = __uint_as_float(dj & 0xffff0000u);
          lo *= ck; hi *= ck;
          const unsigned lr = __float_as_uint(lo) + 0x8000u;  // round-half-up
          const unsigned hr = __float_as_uint(hi) + 0x8000u;
          (&r.x)[j] = __builtin_amdgcn_perm(hr, lr, 0x07060302u); // {hi16(hr),hi16(lr)}
        }
        const int gc = (ac0 >> 3) + m;                 // global chunk index
        const int slot = gc ^ (ar & 7);
        *reinterpret_cast<uint4*>(As + ar * BK + slot * 8) = r;
      }
      // B tile for knot k
      #pragma unroll
      for (int it = 0; it < 4; it++) {
        const int rr = srow + it * 32;
        __builtin_amdgcn_global_load_lds(
            (const __attribute__((address_space(1))) void*)(Bbase + (size_t)rr * 4096 + k * 1024 + kb0 + sgc),
            (__attribute__((address_space(3))) void*)(Bs + rr * BK + scc * 8), 16, 0, 0);
      }
      __syncthreads();

      #pragma unroll
      for (int kk = 0; kk < BK; kk += 32) {
        bf16x8 af[4], bfr[4];
        #pragma unroll
        for (int mi = 0; mi < 4; mi++) {
          const int r = wr + mi * 16 + fm;
          const int lc = ((kk >> 3) + fq) ^ (fm & 7);
          af[mi] = *reinterpret_cast<const bf16x8*>(As + r * BK + lc * 8);
        }
        #pragma unroll
        for (int ni = 0; ni < 4; ni++) {
          const int r = wc + ni * 16 + fm;
          const int lc = ((kk >> 3) + fq) ^ (fm & 7);
          bfr[ni] = *reinterpret_cast<const bf16x8*>(Bs + r * BK + lc * 8);
        }
        #pragma unroll
        for (int mi = 0; mi < 4; mi++)
          #pragma unroll
          for (int ni = 0; ni < 4; ni++)
            acc[mi][ni] = __builtin_amdgcn_mfma_f32_16x16x32_bf16(
                af[mi], bfr[ni], acc[mi][ni], 0, 0, 0);
      }
      __syncthreads();
    }
  }

  // ---- epilogue: + sum_k c_k*bias_k, elu, fp32 store
  #pragma unroll
  for (int mi = 0; mi < 4; mi++) {
    const int rloc = wr + mi * 16 + (fq << 2);           // local row base
    const int rbase = row0 + rloc;
    float4 cfs4[4];
    #pragma unroll
    for (int r = 0; r < 4; r++)
      cfs4[r] = *reinterpret_cast<const float4*>(cfs[rloc + r]);
    #pragma unroll
    for (int ni = 0; ni < 4; ni++) {
      const int col = col0 + wc + ni * 16 + fm;
      const float b0 = bias[col];
      const float b1 = bias[OUT_DIM + col];
      const float b2 = bias[2 * OUT_DIM + col];
      const float b3 = bias[3 * OUT_DIM + col];
      #pragma unroll
      for (int r = 0; r < 4; r++) {
        float v = acc[mi][ni][r]
                + cfs4[r].x * b0 + cfs4[r].y * b1 + cfs4[r].z * b2 + cfs4[r].w * b3;
        v = (v > 0.0f) ? v : expm1f(v);   // elu, alpha=1
        out[(size_t)(rbase + r) * OUT_DIM + col] = v;
      }
    }
  }
}

extern "C" void kernel_launch(void* const* d_in, const int* in_sizes, int n_in,
                              void* d_out, int out_size, void* d_ws, size_t ws_size,
                              hipStream_t stream) {
  const float* x  = (const float*)d_in[0];   // (8192, 1025)
  const float* wk = (const float*)d_in[1];   // (4, 1024, 1024)
  const float* bk = (const float*)d_in[2];   // (4, 1024)
  float* out = (float*)d_out;                // (8192, 1024) fp32

  char* ws = (char*)d_ws;
  unsigned short* Wb = (unsigned short*)ws;                     // 8 MB
  unsigned short* F  = (unsigned short*)(ws + (16u << 20));     // 16 MB

  hipLaunchKernelGGL(prep_kernel, dim3(4096 + NROWS), dim3(256), 0, stream, x, wk, Wb, F);
  hipLaunchKernelGGL(gemm_kernel, dim3(OUT_DIM / BN, NROWS / BM), dim3(256), 0, stream,
                     F, Wb, x, bk, out);
}

// Round 4
// 161.340 us; speedup vs baseline: 1.2333x; 1.1294x over previous
//
#include <hip/hip_runtime.h>
#include <math.h>

#define IN_DIM 1024
#define OUT_DIM 1024
#define NROWS 8192
#define XSTRIDE 1025   // x rows: 1024 feats + 1 phase

typedef __attribute__((ext_vector_type(8))) short bf16x8;
typedef __attribute__((ext_vector_type(4))) float f32x4;

static __device__ __forceinline__ unsigned f2bf(float f) {
  union { float f; unsigned u; } v; v.f = f;
  unsigned u = v.u;
  return (u + 0x7fffu + ((u >> 16) & 1u)) >> 16;  // RTNE
}

// ---- prep:
//  blocks [0,2048):    W(4,1024,1024) f32 -> Wall bf16, row g=(o&15)|(k<<4)|((o>>4)<<6)
//  blocks [2048,10240): feats -> F bf16 (8192x1024); thread 0 also writes coef[b] (float4)
__global__ __launch_bounds__(256) void prep_kernel(
    const float* __restrict__ x, const float* __restrict__ W,
    unsigned short* __restrict__ Wb, unsigned short* __restrict__ F,
    float* __restrict__ coef)
{
  const int blk = blockIdx.x;
  if (blk < 2048) {
    const int t = blk * 256 + threadIdx.x;
    const int flat = t * 8;                    // 8 elems of W
    const int k = flat >> 20;
    const int o = (flat >> 10) & 1023;
    const int i = flat & 1023;                 // multiple of 8
    const float4 fa = *reinterpret_cast<const float4*>(W + flat);
    const float4 fb = *reinterpret_cast<const float4*>(W + flat + 4);
    uint4 pk;
    pk.x = f2bf(fa.x) | (f2bf(fa.y) << 16);
    pk.y = f2bf(fa.z) | (f2bf(fa.w) << 16);
    pk.z = f2bf(fb.x) | (f2bf(fb.y) << 16);
    pk.w = f2bf(fb.z) | (f2bf(fb.w) << 16);
    const int g = (o & 15) | (k << 4) | ((o >> 4) << 6);
    *reinterpret_cast<uint4*>(Wb + (size_t)g * 1024 + i) = pk;
  } else {
    const int b = blk - 2048;
    const float* xr = x + (size_t)b * XSTRIDE;
    const int i = threadIdx.x * 4;
    ushort4 vv;
    vv.x = (unsigned short)f2bf(xr[i]);     vv.y = (unsigned short)f2bf(xr[i + 1]);
    vv.z = (unsigned short)f2bf(xr[i + 2]); vv.w = (unsigned short)f2bf(xr[i + 3]);
    *reinterpret_cast<ushort4*>(F + (size_t)b * 1024 + i) = vv;
    if (threadIdx.x == 0) {
      const float ps = 4.0f * xr[IN_DIM];
      const int ip = (int)ps;            // trunc, ps in [0,4)
      const int i1 = ip & 3;
      const float mu = ps - (float)ip;
      const float mu2 = mu * mu, mu3 = mu2 * mu;
      const float c0 = -0.5f * mu3 +        mu2 - 0.5f * mu;
      const float c1 =  1.5f * mu3 - 2.5f * mu2 + 1.0f;
      const float c2 = -1.5f * mu3 + 2.0f * mu2 + 0.5f * mu;
      const float c3 =  0.5f * mu3 - 0.5f * mu2;
      const int d0 = (0-i1)&3, d1 = (1-i1)&3, d2 = (2-i1)&3, d3 = (3-i1)&3;
      float4 cv;
      cv.x = d0==0 ? c1 : d0==1 ? c2 : d0==2 ? c3 : c0;
      cv.y = d1==0 ? c1 : d1==1 ? c2 : d1==2 ? c3 : c0;
      cv.z = d2==0 ? c1 : d2==1 ? c2 : d2==2 ? c3 : c0;
      cv.w = d3==0 ? c1 : d3==1 ? c2 : d3==2 ? c3 : c0;
      *reinterpret_cast<float4*>(coef + (size_t)b * 4) = cv;
    }
  }
}

// ---- GEMM: C'(8192 x 4096) = F . Wall^T, knots interleaved in N so that
// fragment ni == knot index; cubic combine + bias + elu fused per-lane in epilogue.
#define BM 128
#define BN 128   // g-columns = 32 o's x 4 knots
#define BK 64

__global__ __launch_bounds__(256, 4) void gemm_kernel(
    const unsigned short* __restrict__ F,    // 8192x1024 bf16
    const unsigned short* __restrict__ Wb,   // 4096x1024 bf16, g-layout
    const float* __restrict__ coef,          // 8192x4 f32
    const float* __restrict__ bias,          // 4x1024 f32
    float* __restrict__ out)
{
  __shared__ unsigned short As[BM * BK];   // 16 KB
  __shared__ unsigned short Bs[BN * BK];   // 16 KB
  __shared__ float cfs[BM][4];             // 2 KB

  const int tid  = threadIdx.x;
  const int wave = tid >> 6;
  const int lane = tid & 63;
  const int row0  = blockIdx.y * BM;
  const int col0g = blockIdx.x * BN;       // g-row base of Wall

  if (tid < BM)
    *reinterpret_cast<float4*>(cfs[tid]) =
        *reinterpret_cast<const float4*>(coef + (size_t)(row0 + tid) * 4);
  // (first __syncthreads below orders this before any epilogue read)

  // staging: thread t -> LDS slot t*16B; XOR chunk swizzle on global source
  const int srow = tid >> 3;
  const int scc  = tid & 7;
  const int sgc  = (scc ^ (srow & 7)) * 8;

  const int wr = (wave >> 1) * 64;
  const int wc = (wave & 1) * 64;
  const int fm = lane & 15;
  const int fq = lane >> 4;

  f32x4 acc[4][4];   // [mi][ni=knot]
  const f32x4 zero = {0.f, 0.f, 0.f, 0.f};
  #pragma unroll
  for (int a = 0; a < 4; a++)
    #pragma unroll
    for (int b = 0; b < 4; b++)
      acc[a][b] = zero;

  const unsigned short* Abase = F  + (size_t)row0  * 1024;
  const unsigned short* Bbase = Wb + (size_t)col0g * 1024;

  for (int kb = 0; kb < 1024; kb += BK) {
    #pragma unroll
    for (int it = 0; it < 4; it++) {
      const int r = srow + it * 32;   // (r&7)==(srow&7): swizzle invariant
      __builtin_amdgcn_global_load_lds(
          (const __attribute__((address_space(1))) void*)(Abase + (size_t)r * 1024 + kb + sgc),
          (__attribute__((address_space(3))) void*)(As + r * BK + scc * 8), 16, 0, 0);
      __builtin_amdgcn_global_load_lds(
          (const __attribute__((address_space(1))) void*)(Bbase + (size_t)r * 1024 + kb + sgc),
          (__attribute__((address_space(3))) void*)(Bs + r * BK + scc * 8), 16, 0, 0);
    }
    __syncthreads();

    #pragma unroll
    for (int kk = 0; kk < BK; kk += 32) {
      bf16x8 af[4], bfr[4];
      #pragma unroll
      for (int mi = 0; mi < 4; mi++) {
        const int r  = wr + mi * 16 + fm;
        const int lc = ((kk >> 3) + fq) ^ (fm & 7);
        af[mi] = *reinterpret_cast<const bf16x8*>(As + r * BK + lc * 8);
      }
      #pragma unroll
      for (int ni = 0; ni < 4; ni++) {
        const int r  = wc + ni * 16 + fm;
        const int lc = ((kk >> 3) + fq) ^ (fm & 7);
        bfr[ni] = *reinterpret_cast<const bf16x8*>(Bs + r * BK + lc * 8);
      }
      #pragma unroll
      for (int mi = 0; mi < 4; mi++)
        #pragma unroll
        for (int ni = 0; ni < 4; ni++)
          acc[mi][ni] = __builtin_amdgcn_mfma_f32_16x16x32_bf16(
              af[mi], bfr[ni], acc[mi][ni], 0, 0, 0);
    }
    __syncthreads();
  }

  // ---- epilogue: v = sum_k c_k*(acc_k + bias_k[o]); elu; dense store
  const int o = fm + 16 * (2 * blockIdx.x + (wave & 1));   // this lane's output column
  const float b0 = bias[o];
  const float b1 = bias[OUT_DIM + o];
  const float b2 = bias[2 * OUT_DIM + o];
  const float b3 = bias[3 * OUT_DIM + o];
  #pragma unroll
  for (int mi = 0; mi < 4; mi++) {
    #pragma unroll
    for (int r = 0; r < 4; r++) {
      const int rloc = wr + mi * 16 + (fq << 2) + r;
      const float4 c = *reinterpret_cast<const float4*>(cfs[rloc]);
      float v = c.x * (acc[mi][0][r] + b0)
              + c.y * (acc[mi][1][r] + b1)
              + c.z * (acc[mi][2][r] + b2)
              + c.w * (acc[mi][3][r] + b3);
      v = (v > 0.0f) ? v : expm1f(v);   // elu, alpha=1
      out[(size_t)(row0 + rloc) * OUT_DIM + o] = v;
    }
  }
}

extern "C" void kernel_launch(void* const* d_in, const int* in_sizes, int n_in,
                              void* d_out, int out_size, void* d_ws, size_t ws_size,
                              hipStream_t stream) {
  const float* x  = (const float*)d_in[0];   // (8192, 1025)
  const float* wk = (const float*)d_in[1];   // (4, 1024, 1024)
  const float* bk = (const float*)d_in[2];   // (4, 1024)
  float* out = (float*)d_out;                // (8192, 1024) fp32

  char* ws = (char*)d_ws;
  unsigned short* Wb = (unsigned short*)ws;                   // 8 MB
  unsigned short* F  = (unsigned short*)(ws + (8u << 20));    // 16 MB
  float* coef        = (float*)(ws + (24u << 20));            // 128 KB

  hipLaunchKernelGGL(prep_kernel, dim3(2048 + NROWS), dim3(256), 0, stream,
                     x, wk, Wb, F, coef);
  hipLaunchKernelGGL(gemm_kernel, dim3(4096 / BN, NROWS / BM), dim3(256), 0, stream,
                     F, Wb, coef, bk, out);
}

// Round 5
// 161.148 us; speedup vs baseline: 1.2348x; 1.0012x over previous
//
#include <hip/hip_runtime.h>
#include <math.h>

#define IN_DIM 1024
#define OUT_DIM 1024
#define NROWS 8192
#define XSTRIDE 1025   // x rows: 1024 feats + 1 phase

typedef __attribute__((ext_vector_type(8))) short bf16x8;
typedef __attribute__((ext_vector_type(4))) float f32x4;

static __device__ __forceinline__ unsigned f2bf(float f) {
  union { float f; unsigned u; } v; v.f = f;
  unsigned u = v.u;
  return (u + 0x7fffu + ((u >> 16) & 1u)) >> 16;  // RTNE
}

// ---- prep:
//  blocks [0,2048):    W(4,1024,1024) f32 -> Wall bf16, row g=(o&15)|(k<<4)|((o>>4)<<6)
//  blocks [2048,10240): feats -> F bf16 (8192x1024); thread 0 also writes coef[b] (float4)
__global__ __launch_bounds__(256) void prep_kernel(
    const float* __restrict__ x, const float* __restrict__ W,
    unsigned short* __restrict__ Wb, unsigned short* __restrict__ F,
    float* __restrict__ coef)
{
  const int blk = blockIdx.x;
  if (blk < 2048) {
    const int t = blk * 256 + threadIdx.x;
    const int flat = t * 8;                    // 8 elems of W
    const int k = flat >> 20;
    const int o = (flat >> 10) & 1023;
    const int i = flat & 1023;                 // multiple of 8
    const float4 fa = *reinterpret_cast<const float4*>(W + flat);
    const float4 fb = *reinterpret_cast<const float4*>(W + flat + 4);
    uint4 pk;
    pk.x = f2bf(fa.x) | (f2bf(fa.y) << 16);
    pk.y = f2bf(fa.z) | (f2bf(fa.w) << 16);
    pk.z = f2bf(fb.x) | (f2bf(fb.y) << 16);
    pk.w = f2bf(fb.z) | (f2bf(fb.w) << 16);
    const int g = (o & 15) | (k << 4) | ((o >> 4) << 6);
    *reinterpret_cast<uint4*>(Wb + (size_t)g * 1024 + i) = pk;
  } else {
    const int b = blk - 2048;
    const float* xr = x + (size_t)b * XSTRIDE;
    const int i = threadIdx.x * 4;
    ushort4 vv;
    vv.x = (unsigned short)f2bf(xr[i]);     vv.y = (unsigned short)f2bf(xr[i + 1]);
    vv.z = (unsigned short)f2bf(xr[i + 2]); vv.w = (unsigned short)f2bf(xr[i + 3]);
    *reinterpret_cast<ushort4*>(F + (size_t)b * 1024 + i) = vv;
    if (threadIdx.x == 0) {
      const float ps = 4.0f * xr[IN_DIM];
      const int ip = (int)ps;            // trunc, ps in [0,4)
      const int i1 = ip & 3;
      const float mu = ps - (float)ip;
      const float mu2 = mu * mu, mu3 = mu2 * mu;
      const float c0 = -0.5f * mu3 +        mu2 - 0.5f * mu;
      const float c1 =  1.5f * mu3 - 2.5f * mu2 + 1.0f;
      const float c2 = -1.5f * mu3 + 2.0f * mu2 + 0.5f * mu;
      const float c3 =  0.5f * mu3 - 0.5f * mu2;
      const int d0 = (0-i1)&3, d1 = (1-i1)&3, d2 = (2-i1)&3, d3 = (3-i1)&3;
      float4 cv;
      cv.x = d0==0 ? c1 : d0==1 ? c2 : d0==2 ? c3 : c0;
      cv.y = d1==0 ? c1 : d1==1 ? c2 : d1==2 ? c3 : c0;
      cv.z = d2==0 ? c1 : d2==1 ? c2 : d2==2 ? c3 : c0;
      cv.w = d3==0 ? c1 : d3==1 ? c2 : d3==2 ? c3 : c0;
      *reinterpret_cast<float4*>(coef + (size_t)b * 4) = cv;
    }
  }
}

// ---- GEMM: C'(8192 x 4096) = F . Wall^T, knots interleaved in N so that
// fragment ni == knot index; cubic combine + bias + elu fused per-lane in epilogue.
#define BM 128
#define BN 128   // g-columns = 32 o's x 4 knots
#define BK 64

__global__ __launch_bounds__(256, 4) void gemm_kernel(
    const unsigned short* __restrict__ F,    // 8192x1024 bf16
    const unsigned short* __restrict__ Wb,   // 4096x1024 bf16, g-layout
    const float* __restrict__ coef,          // 8192x4 f32
    const float* __restrict__ bias,          // 4x1024 f32
    float* __restrict__ out)
{
  __shared__ unsigned short As[BM * BK];   // 16 KB
  __shared__ unsigned short Bs[BN * BK];   // 16 KB  (32 KB total, no cfs array)

  const int tid  = threadIdx.x;
  const int wave = tid >> 6;
  const int lane = tid & 63;
  const int row0  = blockIdx.y * BM;
  const int col0g = blockIdx.x * BN;       // g-row base of Wall

  // staging: thread t -> LDS slot t*16B; XOR chunk swizzle on global source
  const int srow = tid >> 3;
  const int scc  = tid & 7;
  const int sgc  = (scc ^ (srow & 7)) * 8;

  const int wr = (wave >> 1) * 64;
  const int wc = (wave & 1) * 64;
  const int fm = lane & 15;
  const int fq = lane >> 4;

  f32x4 acc[4][4];   // [mi][ni=knot]
  const f32x4 zero = {0.f, 0.f, 0.f, 0.f};
  #pragma unroll
  for (int a = 0; a < 4; a++)
    #pragma unroll
    for (int b = 0; b < 4; b++)
      acc[a][b] = zero;

  const unsigned short* Abase = F  + (size_t)row0  * 1024;
  const unsigned short* Bbase = Wb + (size_t)col0g * 1024;

  for (int kb = 0; kb < 1024; kb += BK) {
    #pragma unroll
    for (int it = 0; it < 4; it++) {
      const int r = srow + it * 32;   // (r&7)==(srow&7): swizzle invariant
      __builtin_amdgcn_global_load_lds(
          (const __attribute__((address_space(1))) void*)(Abase + (size_t)r * 1024 + kb + sgc),
          (__attribute__((address_space(3))) void*)(As + r * BK + scc * 8), 16, 0, 0);
      __builtin_amdgcn_global_load_lds(
          (const __attribute__((address_space(1))) void*)(Bbase + (size_t)r * 1024 + kb + sgc),
          (__attribute__((address_space(3))) void*)(Bs + r * BK + scc * 8), 16, 0, 0);
    }
    __syncthreads();

    #pragma unroll
    for (int kk = 0; kk < BK; kk += 32) {
      bf16x8 af[4], bfr[4];
      #pragma unroll
      for (int mi = 0; mi < 4; mi++) {
        const int r  = wr + mi * 16 + fm;
        const int lc = ((kk >> 3) + fq) ^ (fm & 7);
        af[mi] = *reinterpret_cast<const bf16x8*>(As + r * BK + lc * 8);
      }
      #pragma unroll
      for (int ni = 0; ni < 4; ni++) {
        const int r  = wc + ni * 16 + fm;
        const int lc = ((kk >> 3) + fq) ^ (fm & 7);
        bfr[ni] = *reinterpret_cast<const bf16x8*>(Bs + r * BK + lc * 8);
      }
      #pragma unroll
      for (int mi = 0; mi < 4; mi++)
        #pragma unroll
        for (int ni = 0; ni < 4; ni++)
          acc[mi][ni] = __builtin_amdgcn_mfma_f32_16x16x32_bf16(
              af[mi], bfr[ni], acc[mi][ni], 0, 0, 0);
    }
    __syncthreads();
  }

  // ---- epilogue: v = sum_k c_k*(acc_k + bias_k[o]); fast elu; dense store
  const int o = fm + 16 * (2 * blockIdx.x + (wave & 1));   // this lane's output column
  const float b0 = bias[o];
  const float b1 = bias[OUT_DIM + o];
  const float b2 = bias[2 * OUT_DIM + o];
  const float b3 = bias[3 * OUT_DIM + o];
  #pragma unroll
  for (int mi = 0; mi < 4; mi++) {
    #pragma unroll
    for (int r = 0; r < 4; r++) {
      const int rloc = wr + mi * 16 + (fq << 2) + r;
      const float4 c = *reinterpret_cast<const float4*>(coef + (size_t)(row0 + rloc) * 4);
      float v = c.x * (acc[mi][0][r] + b0)
              + c.y * (acc[mi][1][r] + b1)
              + c.z * (acc[mi][2][r] + b2)
              + c.w * (acc[mi][3][r] + b3);
      // elu(alpha=1): exp(v)-1 via hw v_exp_f32; abs err ~1e-7 << 4.3e-3 threshold
      const float e = __expf(v) - 1.0f;
      v = (v > 0.0f) ? v : e;
      out[(size_t)(row0 + rloc) * OUT_DIM + o] = v;
    }
  }
}

extern "C" void kernel_launch(void* const* d_in, const int* in_sizes, int n_in,
                              void* d_out, int out_size, void* d_ws, size_t ws_size,
                              hipStream_t stream) {
  const float* x  = (const float*)d_in[0];   // (8192, 1025)
  const float* wk = (const float*)d_in[1];   // (4, 1024, 1024)
  const float* bk = (const float*)d_in[2];   // (4, 1024)
  float* out = (float*)d_out;                // (8192, 1024) fp32

  char* ws = (char*)d_ws;
  unsigned short* Wb = (unsigned short*)ws;                   // 8 MB
  unsigned short* F  = (unsigned short*)(ws + (8u << 20));    // 16 MB
  float* coef        = (float*)(ws + (24u << 20));            // 128 KB

  hipLaunchKernelGGL(prep_kernel, dim3(2048 + NROWS), dim3(256), 0, stream,
                     x, wk, Wb, F, coef);
  hipLaunchKernelGGL(gemm_kernel, dim3(4096 / BN, NROWS / BM), dim3(256), 0, stream,
                     F, Wb, coef, bk, out);
}